// Round 1
// baseline (229.046 us; speedup 1.0000x reference)
//
#include <hip/hip_runtime.h>

#define FH 200
#define FW 200
#define FC 1024
#define POOL 7

typedef float vf4 __attribute__((ext_vector_type(4)));

__device__ __forceinline__ vf4 lerp4(vf4 a, vf4 b, float w1) {
    return a * (1.0f - w1) + b * w1;
}

// Process NPX consecutive px positions (PX0..PX0+NPX-1) for one (n, py).
// All indices/weights are block-uniform scalars; all arrays are indexed with
// compile-time constants under #pragma unroll -> registers, never scratch.
// Loads are phase-separated (issue everything, then compute) so each wave has
// up to 4*NPX independent 16B loads in flight before the first s_waitcnt.
template<int PX0, int NPX>
__device__ __forceinline__ void do_px_chunk(
    const float* __restrict__ row0,   // feat row iy0
    const float* __restrict__ row1,   // feat row iy1
    int x0, int w,
    float fy, bool needY,
    int t, float* __restrict__ obase)
{
    int   ix0[NPX], ix1[NPX];
    float fx[NPX];
    #pragma unroll
    for (int i = 0; i < NPX; ++i) {
        const int px = PX0 + i;
        // Match reference arithmetic order exactly (fp32 throughout).
        const float rx = (float)px * ((float)w / (float)POOL);
        const int xlo = (int)floorf(rx);
        fx[i] = rx - (float)xlo;
        const int xhi = min(xlo + 1, w - 1);
        ix0[i] = min(max(x0 + xlo, 0), FW - 1);
        ix1[i] = min(max(x0 + xhi, 0), FW - 1);
    }

    vf4 a[NPX], b[NPX], c[NPX], d[NPX];

    // Phase 1: issue every needed load before any compute.
    #pragma unroll
    for (int i = 0; i < NPX; ++i)
        a[i] = *(const vf4*)(row0 + ix0[i] * FC + 4 * t);
    #pragma unroll
    for (int i = 0; i < NPX; ++i)
        if (fx[i] != 0.0f)                       // block-uniform branch
            b[i] = *(const vf4*)(row0 + ix1[i] * FC + 4 * t);
    if (needY) {                                 // block-uniform branch
        #pragma unroll
        for (int i = 0; i < NPX; ++i)
            c[i] = *(const vf4*)(row1 + ix0[i] * FC + 4 * t);
        #pragma unroll
        for (int i = 0; i < NPX; ++i)
            if (fx[i] != 0.0f)
                d[i] = *(const vf4*)(row1 + ix1[i] * FC + 4 * t);
    }

    // Phase 2: compute + store (weight-0 paths are exact: b*0 == 0 for finite b).
    #pragma unroll
    for (int i = 0; i < NPX; ++i) {
        const bool needX = (fx[i] != 0.0f);
        vf4 top = needX ? lerp4(a[i], b[i], fx[i]) : a[i];
        vf4 res = top;
        if (needY) {
            vf4 bot = needX ? lerp4(c[i], d[i], fx[i]) : c[i];
            res = lerp4(top, bot, fy);
        }
        __builtin_nontemporal_store(res, (vf4*)(obase + (size_t)(PX0 + i) * FC));
    }
}

// One block per (n, py): 256 threads x float4 = 1024 channels, 7 px positions.
// ROI fetch + y-side addressing amortized 7x vs the old one-block-per-position
// grid; px unrolled in two register chunks (4+3) keeps VGPRs ~<=128 while
// giving up to 16 outstanding loads per wave (old structure: <=4).
__global__ __launch_bounds__(256) void roi_pool_kernel(
    const float* __restrict__ feat,   // (H, W, C)
    const int*   __restrict__ rois,   // (N, 4) = x0, y0, w, h
    float*       __restrict__ out,    // (N, POOL, POOL, C)
    int N)
{
    const int blk = blockIdx.x;
    const int n  = blk / POOL;
    if (n >= N) return;
    const int py = blk % POOL;

    const int4 roi = *(const int4*)(rois + 4 * n);
    const int x0 = roi.x;
    const int y0 = roi.y;
    const int w  = roi.z;
    const int h  = roi.w;

    // y-side (block-invariant across all 7 px).
    const float ry = (float)py * ((float)h / (float)POOL);
    const int ylo = (int)floorf(ry);
    const float fy = ry - (float)ylo;
    const int yhi = min(ylo + 1, h - 1);
    const int iy0 = min(max(y0 + ylo, 0), FH - 1);
    const int iy1 = min(max(y0 + yhi, 0), FH - 1);
    const bool needY = (fy != 0.0f);

    const int t = threadIdx.x;
    const float* row0 = feat + (size_t)iy0 * (FW * FC);
    const float* row1 = feat + (size_t)iy1 * (FW * FC);

    // Output for this (n, py): 7 contiguous 4KB rows.
    float* obase = out + (size_t)blk * (POOL * FC) + 4 * t;

    do_px_chunk<0, 4>(row0, row1, x0, w, fy, needY, t, obase);
    do_px_chunk<4, 3>(row0, row1, x0, w, fy, needY, t, obase);
}

extern "C" void kernel_launch(void* const* d_in, const int* in_sizes, int n_in,
                              void* d_out, int out_size, void* d_ws, size_t ws_size,
                              hipStream_t stream) {
    const float* feat = (const float*)d_in[0];   // (1, 200, 200, 1024) fp32
    const int*   rois = (const int*)d_in[1];     // (300, 4) int32
    float* out = (float*)d_out;                  // (300, 7, 7, 1024) fp32

    const int N = in_sizes[1] / 4;
    const int blocks = N * POOL;
    roi_pool_kernel<<<blocks, 256, 0, stream>>>(feat, rois, out, N);
}

// Round 2
// 226.765 us; speedup vs baseline: 1.0101x; 1.0101x over previous
//
#include <hip/hip_runtime.h>

#define FH 200
#define FW 200
#define FC 1024
#define POOL 7

typedef float vf4 __attribute__((ext_vector_type(4)));

__device__ __forceinline__ vf4 lerp4(vf4 a, vf4 b, float w1) {
    return a * (1.0f - w1) + b * w1;
}

// One block per (n, py, px): 256 threads x float4 = 1024 channels.
// Round-1 lesson: the (n,py)-fused variant (2100 blocks, 8400 waves) was
// +4 us — TLP matters more than ILP here (58800 waves ~= 7 machine-fills).
// This round: round-0 grid + bijective XCD-chunked swizzle so all 49
// positions of one ROI run on ONE XCD (duplicated chunk reads — iy1 of py
// == iy0 of py+1, overlapping x-chunks at small w — hit 4MB L2 at 34.5 TB/s
// instead of L3), + degenerate-index dedupe (skip loads when ix1==ix0 /
// iy1==iy0; identity within 1 ulp, tolerance 0.0156).
// Wave-uniform weight-0 skipping kept: avg 3.45 loads/position.
__global__ __launch_bounds__(256) void roi_pool_kernel(
    const float* __restrict__ feat,   // (H, W, C)
    const int*   __restrict__ rois,   // (N, 4) = x0, y0, w, h
    float*       __restrict__ out,    // (N, POOL, POOL, C)
    int q, int rr)                    // nwg/8, nwg%8 for bijective swizzle
{
    // Bijective XCD-chunked remap (HW round-robins physical block p -> XCD p%8).
    // Residues xcd<rr own chunks of q+1 logical blocks, others q. (m204 form;
    // 14700 % 8 = 4 so the naive %8 remap would not be bijective.)
    const int p   = blockIdx.x;
    const int xcd = p & 7;
    const int k   = p >> 3;
    const int l   = (xcd < rr ? xcd * (q + 1) : rr * (q + 1) + (xcd - rr) * q) + k;

    const int n   = l / (POOL * POOL);
    const int rem = l % (POOL * POOL);
    const int py  = rem / POOL;
    const int px  = rem % POOL;

    const int4 roi = *(const int4*)(rois + 4 * n);
    const int x0 = roi.x;
    const int y0 = roi.y;
    const int w  = roi.z;
    const int h  = roi.w;

    // Match reference arithmetic order exactly (fp32 throughout).
    const float ry = (float)py * ((float)h / (float)POOL);
    const float rx = (float)px * ((float)w / (float)POOL);
    const int ylo = (int)floorf(ry);
    const int xlo = (int)floorf(rx);
    const float fy = ry - (float)ylo;
    const float fx = rx - (float)xlo;
    const int yhi = min(ylo + 1, h - 1);
    const int xhi = min(xlo + 1, w - 1);

    const int iy0 = min(max(y0 + ylo, 0), FH - 1);
    const int iy1 = min(max(y0 + yhi, 0), FH - 1);
    const int ix0 = min(max(x0 + xlo, 0), FW - 1);
    const int ix1 = min(max(x0 + xhi, 0), FW - 1);

    const int t = threadIdx.x;
    const vf4* p00 = (const vf4*)(feat + ((size_t)iy0 * FW + ix0) * FC);
    const vf4* p01 = (const vf4*)(feat + ((size_t)iy0 * FW + ix1) * FC);
    const vf4* p10 = (const vf4*)(feat + ((size_t)iy1 * FW + ix0) * FC);
    const vf4* p11 = (const vf4*)(feat + ((size_t)iy1 * FW + ix1) * FC);

    // Wave-uniform: skip loads whose lerp weight is 0 OR whose index is
    // degenerate (duplicate pointer -> lerp is identity within 1 ulp).
    const bool needX = (fx != 0.0f) && (ix1 != ix0);
    const bool needY = (fy != 0.0f) && (iy1 != iy0);

    // Issue every needed load before any compute.
    vf4 a, b, c, d;
    a = p00[t];
    if (needX) b = p01[t];
    if (needY) c = p10[t];
    if (needX && needY) d = p11[t];

    vf4 top = needX ? lerp4(a, b, fx) : a;
    vf4 res;
    if (needY) {
        vf4 bot = needX ? lerp4(c, d, fx) : c;
        res = lerp4(top, bot, fy);
    } else {
        res = top;
    }

    // out offset for (n,py,px) == l * FC since l = n*49 + py*7 + px.
    float* o = out + (size_t)l * FC + 4 * t;
    __builtin_nontemporal_store(res, (vf4*)o);
}

extern "C" void kernel_launch(void* const* d_in, const int* in_sizes, int n_in,
                              void* d_out, int out_size, void* d_ws, size_t ws_size,
                              hipStream_t stream) {
    const float* feat = (const float*)d_in[0];   // (1, 200, 200, 1024) fp32
    const int*   rois = (const int*)d_in[1];     // (300, 4) int32
    float* out = (float*)d_out;                  // (300, 7, 7, 1024) fp32

    const int N = in_sizes[1] / 4;
    const int nwg = N * POOL * POOL;
    roi_pool_kernel<<<nwg, 256, 0, stream>>>(feat, rois, out, nwg / 8, nwg % 8);
}